// Round 9
// baseline (199.642 us; speedup 1.0000x reference)
//
#include <hip/hip_runtime.h>
#include <cmath>

typedef __attribute__((ext_vector_type(8))) short bf16x8;
typedef __attribute__((ext_vector_type(4))) float f32x4;

#define MFMA16(a,b,c)  __builtin_amdgcn_mfma_f32_16x16x32_bf16((a),(b),(c),0,0,0)

#if __has_builtin(__builtin_amdgcn_exp2f)
#define EXP2F(x) __builtin_amdgcn_exp2f(x)
#else
#define EXP2F(x) exp2f(x)
#endif

// sqrt(128) * log2(e): folded into w_theta/b_theta at wcvt time.
#define KSCALE 16.3222312f

#define NB 4
#define CH 256
#define CI 128
#define NS 4096   // 64*64 spatial

__device__ __forceinline__ unsigned short f2bf(float f) {
    unsigned int u = __builtin_bit_cast(unsigned int, f);
    u += 0x7fffu + ((u >> 16) & 1u);           // RNE
    return (unsigned short)(u >> 16);
}
__device__ __forceinline__ unsigned int pk2(float lo, float hi) {
    return (unsigned int)f2bf(lo) | ((unsigned int)f2bf(hi) << 16);
}
// truncating pack (softmax P only)
__device__ __forceinline__ unsigned int pk2t(float lo, float hi) {
    unsigned int ul = __builtin_bit_cast(unsigned int, lo);
    unsigned int uh = __builtin_bit_cast(unsigned int, hi);
    return (uh & 0xffff0000u) | (ul >> 16);
}
__device__ __forceinline__ float bf2f(unsigned int ush) {   // low 16 bits
    return __builtin_bit_cast(float, ush << 16);
}

// async global->LDS 16B per lane: LDS dest = wave-uniform base + lane*16
__device__ __forceinline__ void gload16(void* lds, const void* g) {
    __builtin_amdgcn_global_load_lds(
        (const __attribute__((address_space(1))) unsigned int*)g,
        (__attribute__((address_space(3))) unsigned int*)lds,
        16, 0, 0);
}

// ---------------------------------------------------------------------------
// Kernel 0: one-time weight convert to bf16 (KSCALE folded into theta).
// ---------------------------------------------------------------------------
__global__ void wcvt_kernel(const float* __restrict__ w_g, const float* __restrict__ w_th,
                            const float* __restrict__ w_ph, const float* __restrict__ w_out,
                            const float* __restrict__ b_g, const float* __restrict__ b_th,
                            const float* __restrict__ b_ph,
                            unsigned short* __restrict__ wbf, float* __restrict__ bsc) {
    int i = blockIdx.x * 256 + threadIdx.x;     // 0..131071
    float v;
    if (i < 32768)        v = w_g[i];
    else if (i < 65536)   v = w_th[i - 32768] * KSCALE;
    else if (i < 98304)   v = w_ph[i - 65536];
    else                  v = w_out[i - 98304];
    wbf[i] = f2bf(v);
    if (i < 128)          bsc[i] = b_g[i];
    else if (i < 256)     bsc[i] = b_th[i - 128] * KSCALE;
    else if (i < 384)     bsc[i] = b_ph[i - 256];
}

// ---------------------------------------------------------------------------
// Kernel 1: projections.  grid(3 weights, 32 s-tiles, 4 batches), 256 thr.
// Staging LDS columns XOR-swizzled (cp ^ ((s4&7)<<2)): write conflicts
// 16-way -> 4-way (lane stride 272 ≡ 16 mod 32 hit only 2 banks). Verified R8.
// ---------------------------------------------------------------------------
__global__ __launch_bounds__(256, 2)
void proj_kernel(const float* __restrict__ x,
                 const unsigned short* __restrict__ wbf, const float* __restrict__ bsc,
                 unsigned short* __restrict__ theta,
                 unsigned short* __restrict__ phi,
                 unsigned short* __restrict__ gT) {
    const int tid  = threadIdx.x;
    const int wid  = tid >> 6;
    const int lane = tid & 63;
    const int quad = lane >> 4;
    const int l15  = lane & 15;
    const int wi    = blockIdx.x;      // 0=g, 1=theta, 2=phi
    const int stile = blockIdx.y;      // 0..31 (128 s each)
    const int n     = blockIdx.z;
    const int s0    = stile * 128;

    const float* xN = x + (size_t)n * CH * NS;
    const unsigned short* W = wbf + (size_t)wi * 32768;
    const float* Bv = bsc + wi * 128;

    __shared__ unsigned int xp[128 * 68];   // [128 s][64 c-pair + 4 pad], swizzled

    f32x4 acc[8][2];
#pragma unroll
    for (int ot = 0; ot < 8; ot++)
#pragma unroll
        for (int st = 0; st < 2; st++) acc[ot][st] = (f32x4){0.f, 0.f, 0.f, 0.f};

    for (int ch = 0; ch < 2; ch++) {       // two 128-channel halves
        __syncthreads();
#pragma unroll
        for (int i = 0; i < 8; i++) {
            int t  = tid + 256 * i;
            int cp = t >> 5;               // 0..63
            int s4 = t & 31;               // 0..31
            int c0 = ch * 128 + cp * 2;
            int cps = cp ^ ((s4 & 7) << 2);            // bank swizzle
            const float* p0 = xN + (size_t)c0 * NS + s0 + s4 * 4;
            float4 a = *(const float4*)p0;
            float4 b = *(const float4*)(p0 + NS);
            xp[(s4 * 4 + 0) * 68 + cps] = pk2(a.x, b.x);
            xp[(s4 * 4 + 1) * 68 + cps] = pk2(a.y, b.y);
            xp[(s4 * 4 + 2) * 68 + cps] = pk2(a.z, b.z);
            xp[(s4 * 4 + 3) * 68 + cps] = pk2(a.w, b.w);
        }
        __syncthreads();
#pragma unroll
        for (int kc = 0; kc < 4; kc++) {
            bf16x8 af[2];
#pragma unroll
            for (int st = 0; st < 2; st++) {
                int row = wid * 32 + st * 16 + l15;
                int col = (kc * 16 + quad * 4) ^ ((((row >> 2) & 7)) << 2);
                af[st] = *(const bf16x8*)(&xp[row * 68 + col]);
            }
#pragma unroll
            for (int ot = 0; ot < 8; ot++) {
                bf16x8 bf = *(const bf16x8*)(W + (size_t)(ot * 16 + l15) * CH + ch * 128 + kc * 32 + quad * 8);
#pragma unroll
                for (int st = 0; st < 2; st++)
                    acc[ot][st] = MFMA16(af[st], bf, acc[ot][st]);
            }
        }
    }
#pragma unroll
    for (int ot = 0; ot < 8; ot++) {
        int o = ot * 16 + l15;
        float bias = Bv[o];
#pragma unroll
        for (int st = 0; st < 2; st++) {
#pragma unroll
            for (int r = 0; r < 4; r++) {
                int sg = s0 + wid * 32 + st * 16 + quad * 4 + r;
                float v = acc[ot][st][r] + bias;
                if (wi == 0)
                    gT[((size_t)n * CI + o) * NS + sg] = f2bf(v);
                else if (wi == 1)
                    theta[((size_t)n * NS + sg) * CI + o] = f2bf(v);
                else
                    phi[((size_t)n * NS + sg) * CI + o] = f2bf(v);
            }
        }
    }
}

// ---------------------------------------------------------------------------
// Kernel 2: flash attention partials.  Phase-interleaved SINGLE-buffer
// pipeline at 3 blocks/CU (48 KB LDS):  K only read by QK, V only by PV, so
//   B1 (drains K(ck)) -> issue V(ck) -> QK(ck) -> B2 (drains V(ck))
//   -> issue K(ck+1) -> softmax+PV(ck)
// gives dbuf-grade load/compute overlap without the second buffer.
// 256 thr (4 waves), q=32/wave; grid(16 = split*4+n, 32 qb) = 512 blocks.
// Softmax: p = exp2(S) (scale-invariant, no overflow).  O bf16 + l fp32.
// ---------------------------------------------------------------------------
__global__ __launch_bounds__(256, 3)
void attn_kernel(const unsigned short* __restrict__ theta,
                 const unsigned short* __restrict__ phi,
                 const unsigned short* __restrict__ gT,
                 unsigned short* __restrict__ Opart,
                 float* __restrict__ lbuf) {
    const int tid  = threadIdx.x;
    const int wid  = tid >> 6;          // 0..3
    const int lane = tid & 63;
    const int quad = lane >> 4;
    const int l15  = lane & 15;
    const int sn    = blockIdx.x;       // 0..15
    const int split = sn >> 2;          // 0..3
    const int n     = sn & 3;
    const int qb    = blockIdx.y;       // 0..31
    const int qbase = qb * 128 + wid * 32;

    const unsigned short* thN = theta + (size_t)n * NS * CI;
    const unsigned short* phN = phi   + (size_t)n * NS * CI;
    const unsigned short* gN  = gT    + (size_t)n * CI * NS;

    // K: [64 s][128 c] (chunk ^ (s&15))           16 KB
    // V: [128 c][64 s] (chunk ^ (c&7))            16 KB
    // P: 4 waves x 2 qt x [16 q][64 s] (^ (q&7))  16 KB    total 48 KB
    __shared__ unsigned short smem[24576];
    unsigned short* Klds = smem;
    unsigned short* Vlds = smem + 8192;
    unsigned short* Plds = smem + 16384;    // + (wid*2+qt)*1024

    bf16x8 qf[2][4];
#pragma unroll
    for (int qt = 0; qt < 2; qt++)
#pragma unroll
        for (int kc = 0; kc < 4; kc++)
            qf[qt][kc] = *(const bf16x8*)(thN + (size_t)(qbase + qt * 16 + l15) * CI + kc * 32 + quad * 8);

    f32x4 O[8][2];    // O^T tiles [ct][qt]: row=c, col=q
#pragma unroll
    for (int ct = 0; ct < 8; ct++)
#pragma unroll
        for (int qt = 0; qt < 2; qt++) O[ct][qt] = (f32x4){0.f, 0.f, 0.f, 0.f};
    float lrun[2] = {0.f, 0.f};

    const int sbase0 = split * 1024;
    const int lh16 = lane >> 4, lm16 = lane & 15;
    const int lh8  = lane >> 3, lm8  = lane & 7;

    // prologue: issue K(0) so it's drained at the first B1
#pragma unroll
    for (int i = 0; i < 4; i++) {
        int seg = wid * 4 + i;                  // 0..15
        int s   = seg * 4 + lh16;               // 0..63
        int j   = lm16 ^ (s & 15);
        gload16(Klds + seg * 512, phN + (size_t)(sbase0 + s) * CI + j * 8);
    }

    for (int ck = 0; ck < 16; ck++) {
        const int sb = sbase0 + ck * 64;
        // B1: drains K(ck) (and V(ck-1) readers finished PV before this)
        __syncthreads();

        // issue V(ck): overlaps QK(ck); drained at B2
#pragma unroll
        for (int i = 0; i < 4; i++) {
            int seg = wid * 4 + i;
            int c   = seg * 8 + lh8;            // 0..127
            int j   = lm8 ^ (c & 7);
            gload16(Vlds + seg * 512, gN + (size_t)c * NS + sb + j * 8);
        }

        // QK^T -> S^T[qt][st]  (reads K only)
        f32x4 S[2][4];
#pragma unroll
        for (int qt = 0; qt < 2; qt++)
#pragma unroll
            for (int st = 0; st < 4; st++) S[qt][st] = (f32x4){0.f, 0.f, 0.f, 0.f};
#pragma unroll
        for (int st = 0; st < 4; st++) {
#pragma unroll
            for (int kc = 0; kc < 4; kc++) {
                int s = st * 16 + l15;
                bf16x8 kf = *(const bf16x8*)(Klds + s * 128 + ((kc * 4 + quad) ^ l15) * 8);
#pragma unroll
                for (int qt = 0; qt < 2; qt++)
                    S[qt][st] = MFMA16(kf, qf[qt][kc], S[qt][st]);
            }
        }

        // B2: drains V(ck); all QK reads of K done
        __syncthreads();

        // issue K(ck+1): overlaps softmax+PV; drained at next B1
        if (ck + 1 < 16) {
            const int sb1 = sbase0 + (ck + 1) * 64;
#pragma unroll
            for (int i = 0; i < 4; i++) {
                int seg = wid * 4 + i;
                int s   = seg * 4 + lh16;
                int j   = lm16 ^ (s & 15);
                gload16(Klds + seg * 512, phN + (size_t)(sb1 + s) * CI + j * 8);
            }
        }

        // softmax: p = exp2(S), P -> LDS bf16
#pragma unroll
        for (int qt = 0; qt < 2; qt++) {
            float rsl = 0.f;
            unsigned int u[8];
#pragma unroll
            for (int st = 0; st < 4; st++) {
                float p0 = EXP2F(S[qt][st][0]);
                float p1 = EXP2F(S[qt][st][1]);
                float p2 = EXP2F(S[qt][st][2]);
                float p3 = EXP2F(S[qt][st][3]);
                rsl += (p0 + p1) + (p2 + p3);
                u[st * 2]     = pk2t(p0, p1);
                u[st * 2 + 1] = pk2t(p2, p3);
            }
            lrun[qt] += rsl;
            unsigned short* Pw = Plds + (wid * 2 + qt) * 1024 + l15 * 64 + (quad & 1) * 4;
#pragma unroll
            for (int st = 0; st < 4; st++) {
                int p = ((st * 2 + (quad >> 1)) ^ (l15 & 7)) * 8;
                *(uint2*)(Pw + p) = make_uint2(u[st * 2], u[st * 2 + 1]);
            }
        }

        // PV: O^T += V^T . P^T  (reads V + P; in-wave P write->read ordering)
#pragma unroll
        for (int kc2 = 0; kc2 < 2; kc2++) {
            bf16x8 pf[2];
#pragma unroll
            for (int qt = 0; qt < 2; qt++)
                pf[qt] = *(const bf16x8*)(Plds + (wid * 2 + qt) * 1024 + l15 * 64 + (((kc2 * 4 + quad) ^ (l15 & 7)) * 8));
#pragma unroll
            for (int ct = 0; ct < 8; ct++) {
                bf16x8 vf = *(const bf16x8*)(Vlds + (ct * 16 + l15) * 64 + (((kc2 * 4 + quad) ^ (l15 & 7)) * 8));
#pragma unroll
                for (int qt = 0; qt < 2; qt++)
                    O[ct][qt] = MFMA16(vf, pf[qt], O[ct][qt]);
            }
        }
    }

    // epilogue: O^T -> Opart[q][c] bf16 (uint4 stores) via per-wave transpose
    __syncthreads();
    float* tb = (float*)smem + wid * 2048;   // 4 waves x 8 KB (K/V region)
    const size_t obase = ((size_t)(split * NB + n)) * NS * CI;
#pragma unroll
    for (int qt = 0; qt < 2; qt++) {
#pragma unroll
        for (int ct = 0; ct < 8; ct++) {
            int p = (ct * 4 + quad) ^ l15;
            *(f32x4*)(tb + l15 * 128 + p * 4) = O[ct][qt];
        }
#pragma unroll
        for (int i = 0; i < 4; i++) {
            int flat = i * 64 + lane;
            int row = flat >> 4, jj = flat & 15;
            f32x4 a = *(const f32x4*)(tb + row * 128 + ((jj * 2) ^ row) * 4);
            f32x4 b = *(const f32x4*)(tb + row * 128 + ((jj * 2 + 1) ^ row) * 4);
            int q = qbase + qt * 16 + row;
            uint4 pkv;
            pkv.x = pk2(a[0], a[1]); pkv.y = pk2(a[2], a[3]);
            pkv.z = pk2(b[0], b[1]); pkv.w = pk2(b[2], b[3]);
            *(uint4*)(Opart + obase + (size_t)q * CI + jj * 8) = pkv;
        }
    }
    lrun[0] += __shfl_xor(lrun[0], 16); lrun[0] += __shfl_xor(lrun[0], 32);
    lrun[1] += __shfl_xor(lrun[1], 16); lrun[1] += __shfl_xor(lrun[1], 32);
    if (quad == 0) {
#pragma unroll
        for (int qt = 0; qt < 2; qt++) {
            int q = qbase + qt * 16 + l15;
            lbuf[(split * NB + n) * NS + q] = lrun[qt];
        }
    }
}

// ---------------------------------------------------------------------------
// Kernel 3: fused merge (4 bf16 partials) + output projection + residual.
// grid(64 s-tiles, 2 o-halves, 4 n) = 512 blocks, 256 thr.
// ---------------------------------------------------------------------------
__global__ __launch_bounds__(256, 4)
void outproj_kernel(const float* __restrict__ x,
                    const unsigned short* __restrict__ wbf,
                    const float* __restrict__ b_out,
                    const unsigned short* __restrict__ Opart,
                    const float* __restrict__ lbuf,
                    float* __restrict__ out) {
    const int tid  = threadIdx.x;
    const int wid  = tid >> 6;
    const int lane = tid & 63;
    const int quad = lane >> 4;
    const int l15  = lane & 15;
    const int oh = blockIdx.y;
    const int n  = blockIdx.z;
    const int sw = blockIdx.x * 64 + wid * 16;
    const int T  = NB * NS;

    const int srow = n * NS + sw + l15;
    float l = 0.f;
#pragma unroll
    for (int k = 0; k < 4; k++) l += lbuf[k * T + srow];
    float rinv = 1.0f / l;

    bf16x8 yb[4];
#pragma unroll
    for (int kc = 0; kc < 4; kc++) {
        float f0 = 0.f, f1 = 0.f, f2 = 0.f, f3 = 0.f;
        float f4 = 0.f, f5 = 0.f, f6 = 0.f, f7 = 0.f;
#pragma unroll
        for (int k = 0; k < 4; k++) {
            uint4 v = *(const uint4*)(Opart + ((size_t)k * T + srow) * CI + kc * 32 + quad * 8);
            f0 += bf2f(v.x & 0xffffu); f1 += bf2f(v.x >> 16);
            f2 += bf2f(v.y & 0xffffu); f3 += bf2f(v.y >> 16);
            f4 += bf2f(v.z & 0xffffu); f5 += bf2f(v.z >> 16);
            f6 += bf2f(v.w & 0xffffu); f7 += bf2f(v.w >> 16);
        }
        union { unsigned int uu[4]; bf16x8 vv; } r;
        r.uu[0] = pk2(f0 * rinv, f1 * rinv);
        r.uu[1] = pk2(f2 * rinv, f3 * rinv);
        r.uu[2] = pk2(f4 * rinv, f5 * rinv);
        r.uu[3] = pk2(f6 * rinv, f7 * rinv);
        yb[kc] = r.vv;
    }

    const unsigned short* wob = wbf + 3 * 32768 + (size_t)oh * 128 * CI;
    f32x4 acc[8];
#pragma unroll
    for (int ot = 0; ot < 8; ot++) acc[ot] = (f32x4){0.f, 0.f, 0.f, 0.f};
#pragma unroll
    for (int kc = 0; kc < 4; kc++) {
#pragma unroll
        for (int ot = 0; ot < 8; ot++) {
            bf16x8 wa = *(const bf16x8*)(wob + (size_t)(ot * 16 + l15) * CI + kc * 32 + quad * 8);
            acc[ot] = MFMA16(wa, yb[kc], acc[ot]);
        }
    }
#pragma unroll
    for (int ot = 0; ot < 8; ot++) {
#pragma unroll
        for (int r = 0; r < 4; r++) {
            int o = oh * 128 + ot * 16 + quad * 4 + r;
            size_t idx = ((size_t)n * CH + o) * NS + sw + l15;
            out[idx] = x[idx] + acc[ot][r] + b_out[o];
        }
    }
}

// ---------------------------------------------------------------------------
extern "C" void kernel_launch(void* const* d_in, const int* in_sizes, int n_in,
                              void* d_out, int out_size, void* d_ws, size_t ws_size,
                              hipStream_t stream) {
    const float* x     = (const float*)d_in[0];
    const float* w_g   = (const float*)d_in[1];
    const float* b_g   = (const float*)d_in[2];
    const float* w_th  = (const float*)d_in[3];
    const float* b_th  = (const float*)d_in[4];
    const float* w_ph  = (const float*)d_in[5];
    const float* b_ph  = (const float*)d_in[6];
    const float* w_out = (const float*)d_in[7];
    const float* b_out = (const float*)d_in[8];
    float* out = (float*)d_out;

    char* ws = (char*)d_ws;
    unsigned short* theta = (unsigned short*)(ws + 0);          //  4 MiB
    unsigned short* phi   = (unsigned short*)(ws + 4194304);    //  4 MiB
    unsigned short* gT    = (unsigned short*)(ws + 8388608);    //  4 MiB
    unsigned short* Opart = (unsigned short*)(ws + 12582912);   // 16 MiB (4 splits bf16)
    float* lbuf  = (float*)(ws + 29360128);                     // 256 KiB
    unsigned short* wbf = (unsigned short*)(ws + 29622272);     // 256 KiB
    float* bsc   = (float*)(ws + 29884416);                     //  1.5 KiB

    wcvt_kernel<<<512, 256, 0, stream>>>(w_g, w_th, w_ph, w_out, b_g, b_th, b_ph, wbf, bsc);
    proj_kernel<<<dim3(3, 32, NB), 256, 0, stream>>>(x, wbf, bsc, theta, phi, gT);
    attn_kernel<<<dim3(16, 32), 256, 0, stream>>>(theta, phi, gT, Opart, lbuf);
    outproj_kernel<<<dim3(64, 2, NB), 256, 0, stream>>>(x, wbf, b_out, Opart, lbuf, out);
}

// Round 10
// 160.709 us; speedup vs baseline: 1.2423x; 1.2423x over previous
//
#include <hip/hip_runtime.h>
#include <cmath>

typedef __attribute__((ext_vector_type(8))) short bf16x8;
typedef __attribute__((ext_vector_type(4))) float f32x4;

#define MFMA16(a,b,c)  __builtin_amdgcn_mfma_f32_16x16x32_bf16((a),(b),(c),0,0,0)

#if __has_builtin(__builtin_amdgcn_exp2f)
#define EXP2F(x) __builtin_amdgcn_exp2f(x)
#else
#define EXP2F(x) exp2f(x)
#endif

// sqrt(128) * log2(e): folded into w_theta/b_theta at wcvt time.
#define KSCALE 16.3222312f

#define NB 4
#define CH 256
#define CI 128
#define NS 4096   // 64*64 spatial

__device__ __forceinline__ unsigned short f2bf(float f) {
    unsigned int u = __builtin_bit_cast(unsigned int, f);
    u += 0x7fffu + ((u >> 16) & 1u);           // RNE
    return (unsigned short)(u >> 16);
}
__device__ __forceinline__ unsigned int pk2(float lo, float hi) {
    return (unsigned int)f2bf(lo) | ((unsigned int)f2bf(hi) << 16);
}
// truncating pack (softmax P only)
__device__ __forceinline__ unsigned int pk2t(float lo, float hi) {
    unsigned int ul = __builtin_bit_cast(unsigned int, lo);
    unsigned int uh = __builtin_bit_cast(unsigned int, hi);
    return (uh & 0xffff0000u) | (ul >> 16);
}
__device__ __forceinline__ float bf2f(unsigned int ush) {   // low 16 bits
    return __builtin_bit_cast(float, ush << 16);
}

// async global->LDS 16B per lane: LDS dest = wave-uniform base + lane*16
__device__ __forceinline__ void gload16(void* lds, const void* g) {
    __builtin_amdgcn_global_load_lds(
        (const __attribute__((address_space(1))) unsigned int*)g,
        (__attribute__((address_space(3))) unsigned int*)lds,
        16, 0, 0);
}

// ---------------------------------------------------------------------------
// Kernel 0: one-time weight convert to bf16 (KSCALE folded into theta).
// ---------------------------------------------------------------------------
__global__ void wcvt_kernel(const float* __restrict__ w_g, const float* __restrict__ w_th,
                            const float* __restrict__ w_ph, const float* __restrict__ w_out,
                            const float* __restrict__ b_g, const float* __restrict__ b_th,
                            const float* __restrict__ b_ph,
                            unsigned short* __restrict__ wbf, float* __restrict__ bsc) {
    int i = blockIdx.x * 256 + threadIdx.x;     // 0..131071
    float v;
    if (i < 32768)        v = w_g[i];
    else if (i < 65536)   v = w_th[i - 32768] * KSCALE;
    else if (i < 98304)   v = w_ph[i - 65536];
    else                  v = w_out[i - 98304];
    wbf[i] = f2bf(v);
    if (i < 128)          bsc[i] = b_g[i];
    else if (i < 256)     bsc[i] = b_th[i - 128] * KSCALE;
    else if (i < 384)     bsc[i] = b_ph[i - 256];
}

// ---------------------------------------------------------------------------
// Kernel 1: FUSED projections — one x staging serves g/theta/phi (x read 1x).
// grid(64 s-tiles of 64, 4 n) = 256 blocks, 512 thr (8 waves).
// Waves: wid&3 -> s-quarter (16 rows), wid>>2 -> o-half (64 outputs).
// LDS x^T [64 s][128 c-pair uints] = 32 KB, column-group swizzle
// g' = g ^ ((row>>2)&7): staging writes hit all 32 banks; 16-lane spans of
// consecutive s4 give 256 B-contiguous global reads (verified correct in R6).
// ---------------------------------------------------------------------------
__global__ __launch_bounds__(512, 2)
void proj_kernel(const float* __restrict__ x,
                 const unsigned short* __restrict__ wbf, const float* __restrict__ bsc,
                 unsigned short* __restrict__ theta,
                 unsigned short* __restrict__ phi,
                 unsigned short* __restrict__ gT) {
    const int tid  = threadIdx.x;
    const int wid  = tid >> 6;         // 0..7
    const int lane = tid & 63;
    const int quad = lane >> 4;
    const int l15  = lane & 15;
    const int stile = blockIdx.x;      // 0..63
    const int n     = blockIdx.y;
    const int s0    = stile * 64;

    const float* xN = x + (size_t)n * CH * NS;

    __shared__ unsigned int xp[64 * 128];   // 32 KB, swizzled

    // stage: 2048 tasks (128 c-pairs x 16 s-spans of float4), 4/thread
#pragma unroll
    for (int i = 0; i < 4; i++) {
        int t  = i * 512 + tid;
        int s4 = t & 15;
        int cp = t >> 4;                    // 0..127
        const float* p0 = xN + (size_t)(2 * cp) * NS + s0 + s4 * 4;
        float4 a = *(const float4*)p0;
        float4 b = *(const float4*)(p0 + NS);
        int col = (((cp >> 2) ^ (s4 & 7)) << 2) | (cp & 3);   // row>>2 == s4
        unsigned int* xr = xp + (s4 * 4) * 128 + col;
        xr[0]   = pk2(a.x, b.x);
        xr[128] = pk2(a.y, b.y);
        xr[256] = pk2(a.z, b.z);
        xr[384] = pk2(a.w, b.w);
    }
    __syncthreads();

    const int srow = (wid & 3) * 16 + l15;
    const int oh   = wid >> 2;              // o-half
    const int sw7  = (srow >> 2) & 7;
#pragma unroll
    for (int wi = 0; wi < 3; wi++) {
        f32x4 acc[4];
#pragma unroll
        for (int ot = 0; ot < 4; ot++) acc[ot] = (f32x4){0.f, 0.f, 0.f, 0.f};
        const unsigned short* W = wbf + (size_t)wi * 32768 + (size_t)oh * 64 * CH;
#pragma unroll
        for (int kc = 0; kc < 8; kc++) {
            bf16x8 af = *(const bf16x8*)(&xp[srow * 128 + (((kc * 4 + quad) ^ sw7) << 2)]);
#pragma unroll
            for (int ot = 0; ot < 4; ot++) {
                bf16x8 wf = *(const bf16x8*)(W + (size_t)(ot * 16 + l15) * CH + kc * 32 + quad * 8);
                acc[ot] = MFMA16(af, wf, acc[ot]);
            }
        }
        const float* Bv = bsc + wi * 128 + oh * 64;
#pragma unroll
        for (int ot = 0; ot < 4; ot++) {
            int o = oh * 64 + ot * 16 + l15;
            float bias = Bv[ot * 16 + l15];
#pragma unroll
            for (int r = 0; r < 4; r++) {
                int sg = s0 + (wid & 3) * 16 + quad * 4 + r;
                float v = acc[ot][r] + bias;
                if (wi == 0)
                    gT[((size_t)n * CI + o) * NS + sg] = f2bf(v);
                else if (wi == 1)
                    theta[((size_t)n * NS + sg) * CI + o] = f2bf(v);
                else
                    phi[((size_t)n * NS + sg) * CI + o] = f2bf(v);
            }
        }
    }
}

// ---------------------------------------------------------------------------
// Kernel 2: flash attention partials (exact R7 structure: measured 44.3 us).
// 256 thr (4 waves), q=32/wave, 64-s chunks, K/V double-buffer with
// prefetch-after-barrier, 80 KB LDS -> 2 blocks/CU.
// grid(16 = split*4+n, 32 qb) = 512 blocks.
// Softmax: p = exp2(S) (scale-invariant; no overflow).  O bf16 + l fp32.
// ---------------------------------------------------------------------------
__global__ __launch_bounds__(256, 2)
void attn_kernel(const unsigned short* __restrict__ theta,
                 const unsigned short* __restrict__ phi,
                 const unsigned short* __restrict__ gT,
                 unsigned short* __restrict__ Opart,
                 float* __restrict__ lbuf) {
    const int tid  = threadIdx.x;
    const int wid  = tid >> 6;          // 0..3
    const int lane = tid & 63;
    const int quad = lane >> 4;
    const int l15  = lane & 15;
    const int sn    = blockIdx.x;       // 0..15
    const int split = sn >> 2;          // 0..3
    const int n     = sn & 3;
    const int qb    = blockIdx.y;       // 0..31
    const int qbase = qb * 128 + wid * 32;

    const unsigned short* thN = theta + (size_t)n * NS * CI;
    const unsigned short* phN = phi   + (size_t)n * NS * CI;
    const unsigned short* gN  = gT    + (size_t)n * CI * NS;

    // K dbuf: 2 x [64 s][128 c] (chunk ^ (s&15))   32 KB
    // V dbuf: 2 x [128 c][64 s] (chunk ^ (c&7))    32 KB
    // P: 4 waves x 2 qt x [16 q][64 s] (^ (q&7))   16 KB    total 80 KB
    __shared__ unsigned short smem[40960];
    unsigned short* Kb = smem;              // + cur*8192
    unsigned short* Vb = smem + 16384;      // + cur*8192
    unsigned short* Plds = smem + 32768;    // + (wid*2+qt)*1024

    bf16x8 qf[2][4];
#pragma unroll
    for (int qt = 0; qt < 2; qt++)
#pragma unroll
        for (int kc = 0; kc < 4; kc++)
            qf[qt][kc] = *(const bf16x8*)(thN + (size_t)(qbase + qt * 16 + l15) * CI + kc * 32 + quad * 8);

    f32x4 O[8][2];    // O^T tiles [ct][qt]: row=c, col=q
#pragma unroll
    for (int ct = 0; ct < 8; ct++)
#pragma unroll
        for (int qt = 0; qt < 2; qt++) O[ct][qt] = (f32x4){0.f, 0.f, 0.f, 0.f};
    float lrun[2] = {0.f, 0.f};

    const int sbase0 = split * 1024;
    const int lh16 = lane >> 4, lm16 = lane & 15;
    const int lh8  = lane >> 3, lm8  = lane & 7;

    // stage chunk 0 -> buffer 0 (4 K segs + 4 V segs per wave)
#pragma unroll
    for (int i = 0; i < 4; i++) {
        int seg = wid * 4 + i;                  // 0..15
        int s   = seg * 4 + lh16;               // 0..63
        int j   = lm16 ^ (s & 15);
        gload16(Kb + seg * 512, phN + (size_t)(sbase0 + s) * CI + j * 8);
    }
#pragma unroll
    for (int i = 0; i < 4; i++) {
        int seg = wid * 4 + i;
        int c   = seg * 8 + lh8;                // 0..127
        int j   = lm8 ^ (c & 7);
        gload16(Vb + seg * 512, gN + (size_t)c * NS + sbase0 + j * 8);
    }

    for (int ck = 0; ck < 16; ck++) {
        const int cur = ck & 1, nxt = cur ^ 1;
        unsigned short* Kc = Kb + cur * 8192;
        unsigned short* Vc = Vb + cur * 8192;
        __syncthreads();    // drains cur loads; prev compute done

        if (ck + 1 < 16) {  // async prefetch next chunk
            const int sb1 = sbase0 + (ck + 1) * 64;
#pragma unroll
            for (int i = 0; i < 4; i++) {
                int seg = wid * 4 + i;
                int s   = seg * 4 + lh16;
                int j   = lm16 ^ (s & 15);
                gload16(Kb + nxt * 8192 + seg * 512, phN + (size_t)(sb1 + s) * CI + j * 8);
            }
#pragma unroll
            for (int i = 0; i < 4; i++) {
                int seg = wid * 4 + i;
                int c   = seg * 8 + lh8;
                int j   = lm8 ^ (c & 7);
                gload16(Vb + nxt * 8192 + seg * 512, gN + (size_t)c * NS + sb1 + j * 8);
            }
        }

        // QK^T -> S^T[qt][st]
        f32x4 S[2][4];
#pragma unroll
        for (int qt = 0; qt < 2; qt++)
#pragma unroll
            for (int st = 0; st < 4; st++) S[qt][st] = (f32x4){0.f, 0.f, 0.f, 0.f};
#pragma unroll
        for (int st = 0; st < 4; st++) {
#pragma unroll
            for (int kc = 0; kc < 4; kc++) {
                int s = st * 16 + l15;
                bf16x8 kf = *(const bf16x8*)(Kc + s * 128 + ((kc * 4 + quad) ^ l15) * 8);
#pragma unroll
                for (int qt = 0; qt < 2; qt++)
                    S[qt][st] = MFMA16(kf, qf[qt][kc], S[qt][st]);
            }
        }

        // softmax: p = exp2(S), P -> LDS bf16
#pragma unroll
        for (int qt = 0; qt < 2; qt++) {
            float rsl = 0.f;
            unsigned int u[8];
#pragma unroll
            for (int st = 0; st < 4; st++) {
                float p0 = EXP2F(S[qt][st][0]);
                float p1 = EXP2F(S[qt][st][1]);
                float p2 = EXP2F(S[qt][st][2]);
                float p3 = EXP2F(S[qt][st][3]);
                rsl += (p0 + p1) + (p2 + p3);
                u[st * 2]     = pk2t(p0, p1);
                u[st * 2 + 1] = pk2t(p2, p3);
            }
            lrun[qt] += rsl;
            unsigned short* Pw = Plds + (wid * 2 + qt) * 1024 + l15 * 64 + (quad & 1) * 4;
#pragma unroll
            for (int st = 0; st < 4; st++) {
                int p = ((st * 2 + (quad >> 1)) ^ (l15 & 7)) * 8;
                *(uint2*)(Pw + p) = make_uint2(u[st * 2], u[st * 2 + 1]);
            }
        }

        // PV: O^T += V^T . P^T  (in-wave P write->read ordering)
#pragma unroll
        for (int kc2 = 0; kc2 < 2; kc2++) {
            bf16x8 pf[2];
#pragma unroll
            for (int qt = 0; qt < 2; qt++)
                pf[qt] = *(const bf16x8*)(Plds + (wid * 2 + qt) * 1024 + l15 * 64 + (((kc2 * 4 + quad) ^ (l15 & 7)) * 8));
#pragma unroll
            for (int ct = 0; ct < 8; ct++) {
                bf16x8 vf = *(const bf16x8*)(Vc + (ct * 16 + l15) * 64 + (((kc2 * 4 + quad) ^ (l15 & 7)) * 8));
#pragma unroll
                for (int qt = 0; qt < 2; qt++)
                    O[ct][qt] = MFMA16(vf, pf[qt], O[ct][qt]);
            }
        }
    }

    // epilogue: O^T -> Opart[q][c] bf16 (uint4 stores) via per-wave transpose
    __syncthreads();
    float* tb = (float*)smem + wid * 2048;   // 4 waves x 8 KB (K/V region)
    const size_t obase = ((size_t)(split * NB + n)) * NS * CI;
#pragma unroll
    for (int qt = 0; qt < 2; qt++) {
#pragma unroll
        for (int ct = 0; ct < 8; ct++) {
            int p = (ct * 4 + quad) ^ l15;
            *(f32x4*)(tb + l15 * 128 + p * 4) = O[ct][qt];
        }
#pragma unroll
        for (int i = 0; i < 4; i++) {
            int flat = i * 64 + lane;
            int row = flat >> 4, jj = flat & 15;
            f32x4 a = *(const f32x4*)(tb + row * 128 + ((jj * 2) ^ row) * 4);
            f32x4 b = *(const f32x4*)(tb + row * 128 + ((jj * 2 + 1) ^ row) * 4);
            int q = qbase + qt * 16 + row;
            uint4 pkv;
            pkv.x = pk2(a[0], a[1]); pkv.y = pk2(a[2], a[3]);
            pkv.z = pk2(b[0], b[1]); pkv.w = pk2(b[2], b[3]);
            *(uint4*)(Opart + obase + (size_t)q * CI + jj * 8) = pkv;
        }
    }
    lrun[0] += __shfl_xor(lrun[0], 16); lrun[0] += __shfl_xor(lrun[0], 32);
    lrun[1] += __shfl_xor(lrun[1], 16); lrun[1] += __shfl_xor(lrun[1], 32);
    if (quad == 0) {
#pragma unroll
        for (int qt = 0; qt < 2; qt++) {
            int q = qbase + qt * 16 + l15;
            lbuf[(split * NB + n) * NS + q] = lrun[qt];
        }
    }
}

// ---------------------------------------------------------------------------
// Kernel 3: fused merge (4 bf16 partials) + output projection + residual.
// grid(64 s-tiles, 2 o-halves, 4 n) = 512 blocks, 256 thr.
// ---------------------------------------------------------------------------
__global__ __launch_bounds__(256, 4)
void outproj_kernel(const float* __restrict__ x,
                    const unsigned short* __restrict__ wbf,
                    const float* __restrict__ b_out,
                    const unsigned short* __restrict__ Opart,
                    const float* __restrict__ lbuf,
                    float* __restrict__ out) {
    const int tid  = threadIdx.x;
    const int wid  = tid >> 6;
    const int lane = tid & 63;
    const int quad = lane >> 4;
    const int l15  = lane & 15;
    const int oh = blockIdx.y;
    const int n  = blockIdx.z;
    const int sw = blockIdx.x * 64 + wid * 16;
    const int T  = NB * NS;

    const int srow = n * NS + sw + l15;
    float l = 0.f;
#pragma unroll
    for (int k = 0; k < 4; k++) l += lbuf[k * T + srow];
    float rinv = 1.0f / l;

    bf16x8 yb[4];
#pragma unroll
    for (int kc = 0; kc < 4; kc++) {
        float f0 = 0.f, f1 = 0.f, f2 = 0.f, f3 = 0.f;
        float f4 = 0.f, f5 = 0.f, f6 = 0.f, f7 = 0.f;
#pragma unroll
        for (int k = 0; k < 4; k++) {
            uint4 v = *(const uint4*)(Opart + ((size_t)k * T + srow) * CI + kc * 32 + quad * 8);
            f0 += bf2f(v.x & 0xffffu); f1 += bf2f(v.x >> 16);
            f2 += bf2f(v.y & 0xffffu); f3 += bf2f(v.y >> 16);
            f4 += bf2f(v.z & 0xffffu); f5 += bf2f(v.z >> 16);
            f6 += bf2f(v.w & 0xffffu); f7 += bf2f(v.w >> 16);
        }
        union { unsigned int uu[4]; bf16x8 vv; } r;
        r.uu[0] = pk2(f0 * rinv, f1 * rinv);
        r.uu[1] = pk2(f2 * rinv, f3 * rinv);
        r.uu[2] = pk2(f4 * rinv, f5 * rinv);
        r.uu[3] = pk2(f6 * rinv, f7 * rinv);
        yb[kc] = r.vv;
    }

    const unsigned short* wob = wbf + 3 * 32768 + (size_t)oh * 128 * CI;
    f32x4 acc[8];
#pragma unroll
    for (int ot = 0; ot < 8; ot++) acc[ot] = (f32x4){0.f, 0.f, 0.f, 0.f};
#pragma unroll
    for (int kc = 0; kc < 4; kc++) {
#pragma unroll
        for (int ot = 0; ot < 8; ot++) {
            bf16x8 wa = *(const bf16x8*)(wob + (size_t)(ot * 16 + l15) * CI + kc * 32 + quad * 8);
            acc[ot] = MFMA16(wa, yb[kc], acc[ot]);
        }
    }
#pragma unroll
    for (int ot = 0; ot < 8; ot++) {
#pragma unroll
        for (int r = 0; r < 4; r++) {
            int o = oh * 128 + ot * 16 + quad * 4 + r;
            size_t idx = ((size_t)n * CH + o) * NS + sw + l15;
            out[idx] = x[idx] + acc[ot][r] + b_out[o];
        }
    }
}

// ---------------------------------------------------------------------------
extern "C" void kernel_launch(void* const* d_in, const int* in_sizes, int n_in,
                              void* d_out, int out_size, void* d_ws, size_t ws_size,
                              hipStream_t stream) {
    const float* x     = (const float*)d_in[0];
    const float* w_g   = (const float*)d_in[1];
    const float* b_g   = (const float*)d_in[2];
    const float* w_th  = (const float*)d_in[3];
    const float* b_th  = (const float*)d_in[4];
    const float* w_ph  = (const float*)d_in[5];
    const float* b_ph  = (const float*)d_in[6];
    const float* w_out = (const float*)d_in[7];
    const float* b_out = (const float*)d_in[8];
    float* out = (float*)d_out;

    char* ws = (char*)d_ws;
    unsigned short* theta = (unsigned short*)(ws + 0);          //  4 MiB
    unsigned short* phi   = (unsigned short*)(ws + 4194304);    //  4 MiB
    unsigned short* gT    = (unsigned short*)(ws + 8388608);    //  4 MiB
    unsigned short* Opart = (unsigned short*)(ws + 12582912);   // 16 MiB (4 splits bf16)
    float* lbuf  = (float*)(ws + 29360128);                     // 256 KiB
    unsigned short* wbf = (unsigned short*)(ws + 29622272);     // 256 KiB
    float* bsc   = (float*)(ws + 29884416);                     //  1.5 KiB

    wcvt_kernel<<<512, 256, 0, stream>>>(w_g, w_th, w_ph, w_out, b_g, b_th, b_ph, wbf, bsc);
    proj_kernel<<<dim3(64, NB), 512, 0, stream>>>(x, wbf, bsc, theta, phi, gT);
    attn_kernel<<<dim3(16, 32), 256, 0, stream>>>(theta, phi, gT, Opart, lbuf);
    outproj_kernel<<<dim3(64, 2, NB), 256, 0, stream>>>(x, wbf, b_out, Opart, lbuf, out);
}